// Round 3
// baseline (470.555 us; speedup 1.0000x reference)
//
#include <hip/hip_runtime.h>

#define BSZ 2
#define SEQ 2048
#define DIMN 1024
#define NH 16
#define DH 64

typedef unsigned short ushort_t;
typedef __attribute__((ext_vector_type(8))) short short8;
typedef __attribute__((ext_vector_type(4))) float float4v;

__device__ inline float bf2f(ushort_t h) {
    union { unsigned int u; float f; } c; c.u = ((unsigned int)h) << 16; return c.f;
}
__device__ inline ushort_t f2bf(float f) {
    union { float f; unsigned int u; } c; c.f = f;
    unsigned int u = c.u;
    return (ushort_t)((u + 0x7FFFu + ((u >> 16) & 1u)) >> 16);
}

// C[m,n] = scale * (sum_k A[m,k]*W[n,k] + bias[n])
// A: (M,K) row-major, f32 or bf16 per template; W: (N,K) row-major f32; bias f32.
// Output: f32 or bf16 per template. Internal compute: bf16 MFMA.
template<bool A_IS_F32, bool OUT_IS_F32>
__global__ __launch_bounds__(256) void gemm_bt(
    const void* __restrict__ Ap, const float* __restrict__ W,
    const float* __restrict__ bias, void* __restrict__ Cout,
    int M, int N, int K, float scale)
{
    __shared__ ushort_t As[128 * 32];
    __shared__ ushort_t Bs[128 * 32];
    const int tid  = threadIdx.x;
    const int lane = tid & 63;
    const int w    = tid >> 6;
    const int wm   = w >> 1, wn = w & 1;
    const int quad = lane >> 4;
    const int l16  = lane & 15;
    const int mBase = blockIdx.y * 128;
    const int nBase = blockIdx.x * 128;

    float4v acc[4][4];
    const float4v z4 = {0.f, 0.f, 0.f, 0.f};
#pragma unroll
    for (int i = 0; i < 4; ++i)
#pragma unroll
        for (int j = 0; j < 4; ++j) acc[i][j] = z4;

    for (int k0 = 0; k0 < K; k0 += 32) {
        // prefetch into registers before the barrier
        short8  va_b[2];
        float4v va_f[2][2], vw_f[2][2];
#pragma unroll
        for (int it = 0; it < 2; ++it) {
            int c   = it * 256 + tid;      // 0..511 chunks of 8 elements
            int row = c >> 2;              // 4 chunks per 32-elem row
            int col = (c & 3) * 8;
            if (A_IS_F32) {
                const float* g = (const float*)Ap + (size_t)(mBase + row) * K + k0 + col;
                va_f[it][0] = *(const float4v*)g;
                va_f[it][1] = *(const float4v*)(g + 4);
            } else {
                const ushort_t* g = (const ushort_t*)Ap + (size_t)(mBase + row) * K + k0 + col;
                va_b[it] = *(const short8*)g;
            }
            const float* gw = W + (size_t)(nBase + row) * K + k0 + col;
            vw_f[it][0] = *(const float4v*)gw;
            vw_f[it][1] = *(const float4v*)(gw + 4);
        }
        __syncthreads();   // all waves done reading previous tile
#pragma unroll
        for (int it = 0; it < 2; ++it) {
            int c = it * 256 + tid;
            short8 sa, sw;
            if (A_IS_F32) {
#pragma unroll
                for (int j = 0; j < 8; ++j) sa[j] = (short)f2bf(va_f[it][j >> 2][j & 3]);
            } else {
                sa = va_b[it];
            }
#pragma unroll
            for (int j = 0; j < 8; ++j) sw[j] = (short)f2bf(vw_f[it][j >> 2][j & 3]);
            *(short8*)&As[c * 8] = sa;
            *(short8*)&Bs[c * 8] = sw;
        }
        __syncthreads();   // staging visible

        short8 af[4], bfr[4];
#pragma unroll
        for (int mt = 0; mt < 4; ++mt)
            af[mt] = *(const short8*)&As[(wm * 64 + mt * 16 + l16) * 32 + quad * 8];
#pragma unroll
        for (int nt = 0; nt < 4; ++nt)
            bfr[nt] = *(const short8*)&Bs[(wn * 64 + nt * 16 + l16) * 32 + quad * 8];
#pragma unroll
        for (int mt = 0; mt < 4; ++mt)
#pragma unroll
            for (int nt = 0; nt < 4; ++nt)
                acc[mt][nt] = __builtin_amdgcn_mfma_f32_16x16x32_bf16(af[mt], bfr[nt], acc[mt][nt], 0, 0, 0);
    }

    float bv[4];
#pragma unroll
    for (int nt = 0; nt < 4; ++nt)
        bv[nt] = bias[nBase + wn * 64 + nt * 16 + l16];
#pragma unroll
    for (int mt = 0; mt < 4; ++mt)
#pragma unroll
        for (int nt = 0; nt < 4; ++nt) {
            int colg = nBase + wn * 64 + nt * 16 + l16;
#pragma unroll
            for (int r = 0; r < 4; ++r) {
                int rowg = mBase + wm * 64 + mt * 16 + quad * 4 + r;
                float v  = (acc[mt][nt][r] + bv[nt]) * scale;
                size_t idx = (size_t)rowg * N + colg;
                if (OUT_IS_F32) ((float*)Cout)[idx] = v;
                else            ((ushort_t*)Cout)[idx] = f2bf(v);
            }
        }
}

// Fused flash attention: per block one (b,h) x 128 query rows; K-tile = 64 keys.
// Q/K/V/context are bf16 in workspace.
__global__ __launch_bounds__(256) void attn_kernel(
    const ushort_t* __restrict__ Qp, const ushort_t* __restrict__ Kp,
    const ushort_t* __restrict__ Vp, const int* __restrict__ mask,
    ushort_t* __restrict__ Cp)
{
    __shared__ ushort_t Qs[128 * 64];
    __shared__ ushort_t Ks[64 * 64];
    __shared__ ushort_t Vt[64 * 72];   // [dim][key], pad 8 to break bank stride
    __shared__ ushort_t Ps[4 * 32 * 64];

    const int tid  = threadIdx.x;
    const int lane = tid & 63;
    const int w    = tid >> 6;
    const int quad = lane >> 4;
    const int l16  = lane & 15;
    const int bh   = blockIdx.x;
    const int b    = bh >> 4;
    const int h    = bh & 15;
    const int q0   = blockIdx.y * 128;

    // stage Q tile (128 x 64) through registers
    {
        short8 qreg[4];
#pragma unroll
        for (int it = 0; it < 4; ++it) {
            int c   = it * 256 + tid;      // 0..1023
            int row = c >> 3;              // 8 chunks per row (64 bf16)
            int col = (c & 7) * 8;
            qreg[it] = *(const short8*)(Qp + (size_t)(b * SEQ + q0 + row) * DIMN + h * DH + col);
        }
#pragma unroll
        for (int it = 0; it < 4; ++it) {
            int c = it * 256 + tid;
            *(short8*)&Qs[c * 8] = qreg[it];
        }
    }

    const float4v z4 = {0.f, 0.f, 0.f, 0.f};
    float4v Oacc[2][4];
#pragma unroll
    for (int rt = 0; rt < 2; ++rt)
#pragma unroll
        for (int vt = 0; vt < 4; ++vt) Oacc[rt][vt] = z4;
    float mrow[2][4], lrow[2][4];
#pragma unroll
    for (int rt = 0; rt < 2; ++rt)
#pragma unroll
        for (int r = 0; r < 4; ++r) { mrow[rt][r] = -3e38f; lrow[rt][r] = 0.f; }

    for (int kt0 = 0; kt0 < SEQ; kt0 += 64) {
        // prefetch K tile (64x64) and V chunk into registers
        short8 kreg[2];
#pragma unroll
        for (int it = 0; it < 2; ++it) {
            int c   = it * 256 + tid;  // 0..511
            int row = c >> 3;
            int col = (c & 7) * 8;
            kreg[it] = *(const short8*)(Kp + (size_t)(b * SEQ + kt0 + row) * DIMN + h * DH + col);
        }
        const int vkey  = tid >> 2;
        const int vdseg = (tid & 3) * 16;
        const ushort_t* vg = Vp + (size_t)(b * SEQ + kt0 + vkey) * DIMN + h * DH + vdseg;
        short8 v0 = *(const short8*)vg;
        short8 v1 = *(const short8*)(vg + 8);

        __syncthreads();   // sync A: prev-iter LDS reads complete
#pragma unroll
        for (int it = 0; it < 2; ++it) {
            int c = it * 256 + tid;
            *(short8*)&Ks[c * 8] = kreg[it];
        }
#pragma unroll
        for (int j = 0; j < 8; ++j) {
            Vt[(vdseg + j) * 72 + vkey]     = (ushort_t)v0[j];
            Vt[(vdseg + 8 + j) * 72 + vkey] = (ushort_t)v1[j];
        }
        __syncthreads();   // sync B: staging visible

        // S = Q * K^T  (wave rows [w*32, +32), 64 key cols)
        float4v Sv[2][4];
#pragma unroll
        for (int rt = 0; rt < 2; ++rt)
#pragma unroll
            for (int kt = 0; kt < 4; ++kt) Sv[rt][kt] = z4;
        short8 bk[2][4];
#pragma unroll
        for (int ks = 0; ks < 2; ++ks)
#pragma unroll
            for (int kt = 0; kt < 4; ++kt)
                bk[ks][kt] = *(const short8*)&Ks[(kt * 16 + l16) * 64 + ks * 32 + quad * 8];
#pragma unroll
        for (int rt = 0; rt < 2; ++rt)
#pragma unroll
            for (int ks = 0; ks < 2; ++ks) {
                short8 aq = *(const short8*)&Qs[(w * 32 + rt * 16 + l16) * 64 + ks * 32 + quad * 8];
#pragma unroll
                for (int kt = 0; kt < 4; ++kt)
                    Sv[rt][kt] = __builtin_amdgcn_mfma_f32_16x16x32_bf16(aq, bk[ks][kt], Sv[rt][kt], 0, 0, 0);
            }

        // mask (key position kt0 + kt*16 + l16)
#pragma unroll
        for (int kt = 0; kt < 4; ++kt) {
            int mv = mask[b * SEQ + kt0 + kt * 16 + l16];
            if (mv == 0) {
#pragma unroll
                for (int rt = 0; rt < 2; ++rt)
#pragma unroll
                    for (int r = 0; r < 4; ++r) Sv[rt][kt][r] = -1e30f;
            }
        }

        // online softmax (row = quad*4 + r; rows live in 16-lane groups)
#pragma unroll
        for (int rt = 0; rt < 2; ++rt)
#pragma unroll
            for (int r = 0; r < 4; ++r) {
                float mx = fmaxf(fmaxf(Sv[rt][0][r], Sv[rt][1][r]), fmaxf(Sv[rt][2][r], Sv[rt][3][r]));
#pragma unroll
                for (int d = 1; d < 16; d <<= 1) mx = fmaxf(mx, __shfl_xor(mx, d));
                float mo = mrow[rt][r];
                float mn = fmaxf(mo, mx);
                float alpha = __builtin_expf(mo - mn);   // mo-mn <= 0
                float ps = 0.f;
#pragma unroll
                for (int kt = 0; kt < 4; ++kt) {
                    float p = __builtin_expf(Sv[rt][kt][r] - mn);
                    Sv[rt][kt][r] = p;
                    ps += p;
                }
#pragma unroll
                for (int d = 1; d < 16; d <<= 1) ps += __shfl_xor(ps, d);
                lrow[rt][r] = lrow[rt][r] * alpha + ps;
                mrow[rt][r] = mn;
#pragma unroll
                for (int vt = 0; vt < 4; ++vt) Oacc[rt][vt][r] *= alpha;  // per-row rescale (bugfix)
            }

        // P: C-layout regs -> LDS row-major [row][key] (per-wave region)
#pragma unroll
        for (int rt = 0; rt < 2; ++rt)
#pragma unroll
            for (int kt = 0; kt < 4; ++kt)
#pragma unroll
                for (int r = 0; r < 4; ++r)
                    Ps[w * 2048 + (rt * 16 + quad * 4 + r) * 64 + kt * 16 + l16] = f2bf(Sv[rt][kt][r]);
        __syncthreads();   // sync C: P visible

        // O += P * V
        short8 bvv[2][4];
#pragma unroll
        for (int ks = 0; ks < 2; ++ks)
#pragma unroll
            for (int vt = 0; vt < 4; ++vt)
                bvv[ks][vt] = *(const short8*)&Vt[(vt * 16 + l16) * 72 + ks * 32 + quad * 8];
#pragma unroll
        for (int rt = 0; rt < 2; ++rt)
#pragma unroll
            for (int ks = 0; ks < 2; ++ks) {
                short8 ap = *(const short8*)&Ps[w * 2048 + (rt * 16 + l16) * 64 + ks * 32 + quad * 8];
#pragma unroll
                for (int vt = 0; vt < 4; ++vt)
                    Oacc[rt][vt] = __builtin_amdgcn_mfma_f32_16x16x32_bf16(ap, bvv[ks][vt], Oacc[rt][vt], 0, 0, 0);
            }
    }

    // epilogue: O / l -> context (b, q, h*64+d), bf16 internal
#pragma unroll
    for (int rt = 0; rt < 2; ++rt)
#pragma unroll
        for (int vt = 0; vt < 4; ++vt)
#pragma unroll
            for (int r = 0; r < 4; ++r) {
                int row = q0 + w * 32 + rt * 16 + quad * 4 + r;
                int col = h * DH + vt * 16 + l16;
                float ov = Oacc[rt][vt][r] / lrow[rt][r];
                Cp[(size_t)(b * SEQ + row) * DIMN + col] = f2bf(ov);
            }
}

extern "C" void kernel_launch(void* const* d_in, const int* in_sizes, int n_in,
                              void* d_out, int out_size, void* d_ws, size_t ws_size,
                              hipStream_t stream) {
    // Inputs are FLOAT32 per the reference (jnp.float32); mask is int32.
    const float* x_q = (const float*)d_in[0];
    const float* x_k = (const float*)d_in[1];
    const float* x_v = (const float*)d_in[2];
    const int*   msk = (const int*)d_in[3];
    const float* q_w = (const float*)d_in[4];
    const float* q_b = (const float*)d_in[5];
    const float* k_w = (const float*)d_in[6];
    const float* k_b = (const float*)d_in[7];
    const float* v_w = (const float*)d_in[8];
    const float* v_b = (const float*)d_in[9];
    const float* o_w = (const float*)d_in[10];
    const float* o_b = (const float*)d_in[11];
    float* out = (float*)d_out;

    const size_t NEL = (size_t)BSZ * SEQ * DIMN;  // 4194304
    ushort_t* Qp = (ushort_t*)d_ws;               // bf16 internal buffers
    ushort_t* Kp = Qp + NEL;
    ushort_t* Vp = Kp + NEL;
    ushort_t* Cp = Vp + NEL;

    const int M = BSZ * SEQ;
    dim3 gg(DIMN / 128, M / 128);  // (8, 32)
    gemm_bt<true, false><<<gg, 256, 0, stream>>>(x_q, q_w, q_b, Qp, M, DIMN, DIMN, 0.125f);
    gemm_bt<true, false><<<gg, 256, 0, stream>>>(x_k, k_w, k_b, Kp, M, DIMN, DIMN, 1.0f);
    gemm_bt<true, false><<<gg, 256, 0, stream>>>(x_v, v_w, v_b, Vp, M, DIMN, DIMN, 1.0f);
    attn_kernel<<<dim3(BSZ * NH, SEQ / 128), 256, 0, stream>>>(Qp, Kp, Vp, msk, Cp);
    gemm_bt<false, true><<<gg, 256, 0, stream>>>(Cp, o_w, o_b, out, M, DIMN, DIMN, 1.0f);
}

// Round 4
// 345.269 us; speedup vs baseline: 1.3629x; 1.3629x over previous
//
#include <hip/hip_runtime.h>

#define BSZ 2
#define SEQ 2048
#define DIMN 1024
#define NH 16
#define DH 64
#define LOG2E 1.4426950408889634f

typedef unsigned short ushort_t;
typedef __attribute__((ext_vector_type(8))) short short8;
typedef __attribute__((ext_vector_type(4))) short short4v;
typedef __attribute__((ext_vector_type(4))) float float4v;

// round-half-up bf16 (2 VALU ops; |bias| <= 0.5 ulp, fine for internal tensors)
__device__ __forceinline__ ushort_t f2bf(float f) {
    union { float f; unsigned int u; } c; c.f = f;
    return (ushort_t)((c.u + 0x8000u) >> 16);
}

// ---------------- weight pre-convert (f32 -> bf16), 4 weights ----------------
__global__ __launch_bounds__(256) void cvt_w(
    const float* __restrict__ w0, const float* __restrict__ w1,
    const float* __restrict__ w2, const float* __restrict__ w3,
    ushort_t* __restrict__ o0, ushort_t* __restrict__ o1,
    ushort_t* __restrict__ o2, ushort_t* __restrict__ o3)
{
    const float* s; ushort_t* d;
    switch (blockIdx.y) {
        case 0: s = w0; d = o0; break;
        case 1: s = w1; d = o1; break;
        case 2: s = w2; d = o2; break;
        default: s = w3; d = o3; break;
    }
    int i = (blockIdx.x * 256 + threadIdx.x) * 4;   // grid.x*256*4 == 1M exactly
    float4v v = *(const float4v*)(s + i);
    short4v o;
#pragma unroll
    for (int j = 0; j < 4; ++j) o[j] = (short)f2bf(v[j]);
    *(short4v*)(d + i) = o;
}

// ---------------- GEMM core: C[m,n] = scale*(A.W^T + bias), tile 64x128, BK=32 ----
// A:(M,1024), W:(1024,1024) row-major. LDS rows padded to 40 shorts (20 dw % 32 != 0).
template<bool A_F32, bool W_BF16, bool OUT_F32>
__device__ __forceinline__ void gemm_core(
    const void* __restrict__ Ap, const void* __restrict__ Wp,
    const float* __restrict__ bias, void* __restrict__ Cout,
    float scale, int mBase, int nBase)
{
    __shared__ ushort_t As[64 * 40];
    __shared__ ushort_t Bs[128 * 40];
    const int tid  = threadIdx.x;
    const int lane = tid & 63;
    const int w    = tid >> 6;
    const int quad = lane >> 4;
    const int l16  = lane & 15;

    float4v acc[4][2];
    const float4v z4 = {0.f, 0.f, 0.f, 0.f};
#pragma unroll
    for (int mt = 0; mt < 4; ++mt)
#pragma unroll
        for (int nt = 0; nt < 2; ++nt) acc[mt][nt] = z4;

    const int arow = tid >> 2, acol = (tid & 3) * 8;   // A: 256 chunks of 8
    for (int k0 = 0; k0 < 1024; k0 += 32) {
        // ---- prefetch to regs (before barrier) ----
        float4v af0, af1; short8 ab;
        if (A_F32) {
            const float* g = (const float*)Ap + (size_t)(mBase + arow) * 1024 + k0 + acol;
            af0 = *(const float4v*)g; af1 = *(const float4v*)(g + 4);
        } else {
            ab = *(const short8*)((const ushort_t*)Ap + (size_t)(mBase + arow) * 1024 + k0 + acol);
        }
        short8 wb[2]; float4v wf[2][2];
#pragma unroll
        for (int it = 0; it < 2; ++it) {
            int c = it * 256 + tid, wrow = c >> 2, wcol = (c & 3) * 8;
            if (W_BF16) {
                wb[it] = *(const short8*)((const ushort_t*)Wp + (size_t)(nBase + wrow) * 1024 + k0 + wcol);
            } else {
                const float* g = (const float*)Wp + (size_t)(nBase + wrow) * 1024 + k0 + wcol;
                wf[it][0] = *(const float4v*)g; wf[it][1] = *(const float4v*)(g + 4);
            }
        }
        __syncthreads();   // prev-tile reads done
        {
            short8 sa;
            if (A_F32) {
#pragma unroll
                for (int j = 0; j < 8; ++j) sa[j] = (short)f2bf(j < 4 ? af0[j] : af1[j - 4]);
            } else sa = ab;
            *(short8*)&As[arow * 40 + acol] = sa;
        }
#pragma unroll
        for (int it = 0; it < 2; ++it) {
            int c = it * 256 + tid, wrow = c >> 2, wcol = (c & 3) * 8;
            short8 sw;
            if (W_BF16) sw = wb[it];
            else {
#pragma unroll
                for (int j = 0; j < 8; ++j) sw[j] = (short)f2bf(j < 4 ? wf[it][0][j] : wf[it][1][j - 4]);
            }
            *(short8*)&Bs[wrow * 40 + wcol] = sw;
        }
        __syncthreads();   // staging visible

        short8 afr[4], bfr[2];
#pragma unroll
        for (int mt = 0; mt < 4; ++mt)
            afr[mt] = *(const short8*)&As[(mt * 16 + l16) * 40 + quad * 8];
#pragma unroll
        for (int nt = 0; nt < 2; ++nt)
            bfr[nt] = *(const short8*)&Bs[(w * 32 + nt * 16 + l16) * 40 + quad * 8];
#pragma unroll
        for (int mt = 0; mt < 4; ++mt)
#pragma unroll
            for (int nt = 0; nt < 2; ++nt)
                acc[mt][nt] = __builtin_amdgcn_mfma_f32_16x16x32_bf16(afr[mt], bfr[nt], acc[mt][nt], 0, 0, 0);
    }

    float bv[2];
#pragma unroll
    for (int nt = 0; nt < 2; ++nt) bv[nt] = bias[nBase + w * 32 + nt * 16 + l16];
#pragma unroll
    for (int mt = 0; mt < 4; ++mt)
#pragma unroll
        for (int nt = 0; nt < 2; ++nt) {
            int colg = nBase + w * 32 + nt * 16 + l16;
#pragma unroll
            for (int r = 0; r < 4; ++r) {
                int rowg = mBase + mt * 16 + quad * 4 + r;
                float v = (acc[mt][nt][r] + bv[nt]) * scale;
                size_t idx = (size_t)rowg * 1024 + colg;
                if (OUT_F32) ((float*)Cout)[idx] = v;
                else         ((ushort_t*)Cout)[idx] = f2bf(v);
            }
        }
}

template<bool W_BF16>
__global__ __launch_bounds__(256) void gemm_qkv(
    const float* A0, const float* A1, const float* A2,
    const void* W0, const void* W1, const void* W2,
    const float* b0, const float* b1, const float* b2,
    ushort_t* C0, ushort_t* C1, ushort_t* C2)
{
    int z = blockIdx.z;
    const float* A = (z == 0) ? A0 : (z == 1) ? A1 : A2;
    const void*  W = (z == 0) ? W0 : (z == 1) ? W1 : W2;
    const float* bb = (z == 0) ? b0 : (z == 1) ? b1 : b2;
    ushort_t* C = (z == 0) ? C0 : (z == 1) ? C1 : C2;
    float scale = (z == 0) ? 0.125f * LOG2E : 1.0f;   // Q pre-scaled into log2 domain
    gemm_core<true, W_BF16, false>(A, W, bb, C, scale, blockIdx.y * 64, blockIdx.x * 128);
}

template<bool W_BF16>
__global__ __launch_bounds__(256) void gemm_o(
    const ushort_t* A, const void* W, const float* bias, float* C)
{
    gemm_core<false, W_BF16, true>(A, W, bias, C, 1.0f, blockIdx.y * 64, blockIdx.x * 128);
}

// ---------------- fused flash attention: Q-tile 64, K-tile 64, 4 waves x 16 rows ----
__global__ __launch_bounds__(256) void attn_kernel(
    const ushort_t* __restrict__ Qp, const ushort_t* __restrict__ Kp,
    const ushort_t* __restrict__ Vp, const int* __restrict__ mask,
    ushort_t* __restrict__ Cp)
{
    __shared__ ushort_t Qs[64 * 72];   // [qrow][dim], stride 72 (36 dw == 4 mod 32)
    __shared__ ushort_t Ks[64 * 72];   // [key][dim]
    __shared__ ushort_t Vt[64 * 72];   // [dim][key]
    __shared__ ushort_t Ps[64 * 72];   // [qrow][key], per-wave 16-row slices

    const int tid  = threadIdx.x;
    const int lane = tid & 63;
    const int w    = tid >> 6;
    const int quad = lane >> 4;
    const int l16  = lane & 15;
    const int b    = blockIdx.x >> 4;
    const int h    = blockIdx.x & 15;
    const int q0   = blockIdx.y * 64;

    // stage Q (64x64) through regs; visible after first sync B
    short8 qreg[2];
#pragma unroll
    for (int it = 0; it < 2; ++it) {
        int c = it * 256 + tid, row = c >> 3, col = (c & 7) * 8;
        qreg[it] = *(const short8*)(Qp + (size_t)(b * SEQ + q0 + row) * DIMN + h * DH + col);
    }
#pragma unroll
    for (int it = 0; it < 2; ++it) {
        int c = it * 256 + tid, row = c >> 3, col = (c & 7) * 8;
        *(short8*)&Qs[row * 72 + col] = qreg[it];
    }

    const float4v z4 = {0.f, 0.f, 0.f, 0.f};
    float4v Oacc[4];
#pragma unroll
    for (int vt = 0; vt < 4; ++vt) Oacc[vt] = z4;
    float mrow[4], lrow[4];
#pragma unroll
    for (int r = 0; r < 4; ++r) { mrow[r] = -3e38f; lrow[r] = 0.f; }

    for (int kt0 = 0; kt0 < SEQ; kt0 += 64) {
        // prefetch K tile + V chunk
        short8 kreg[2];
#pragma unroll
        for (int it = 0; it < 2; ++it) {
            int c = it * 256 + tid, row = c >> 3, col = (c & 7) * 8;
            kreg[it] = *(const short8*)(Kp + (size_t)(b * SEQ + kt0 + row) * DIMN + h * DH + col);
        }
        // V: lane = key, wave = 16-dim slab  -> conflict-free transposed writes
        const ushort_t* vg = Vp + (size_t)(b * SEQ + kt0 + lane) * DIMN + h * DH + w * 16;
        short8 v0 = *(const short8*)vg;
        short8 v1 = *(const short8*)(vg + 8);

        __syncthreads();   // sync A: prev-iter LDS reads complete
#pragma unroll
        for (int it = 0; it < 2; ++it) {
            int c = it * 256 + tid, row = c >> 3, col = (c & 7) * 8;
            *(short8*)&Ks[row * 72 + col] = kreg[it];
        }
#pragma unroll
        for (int j = 0; j < 8; ++j) {
            Vt[(w * 16 + j) * 72 + lane]     = (ushort_t)v0[j];
            Vt[(w * 16 + 8 + j) * 72 + lane] = (ushort_t)v1[j];
        }
        __syncthreads();   // sync B: staging visible

        // S = Q K^T  (16 q-rows per wave, 64 keys); S already in log2 units
        float4v Sv[4];
#pragma unroll
        for (int kt = 0; kt < 4; ++kt) Sv[kt] = z4;
#pragma unroll
        for (int ks = 0; ks < 2; ++ks) {
            short8 aq = *(const short8*)&Qs[(w * 16 + l16) * 72 + ks * 32 + quad * 8];
#pragma unroll
            for (int kt = 0; kt < 4; ++kt) {
                short8 bk = *(const short8*)&Ks[(kt * 16 + l16) * 72 + ks * 32 + quad * 8];
                Sv[kt] = __builtin_amdgcn_mfma_f32_16x16x32_bf16(aq, bk, Sv[kt], 0, 0, 0);
            }
        }

        // mask
#pragma unroll
        for (int kt = 0; kt < 4; ++kt) {
            if (mask[b * SEQ + kt0 + kt * 16 + l16] == 0) {
#pragma unroll
                for (int r = 0; r < 4; ++r) Sv[kt][r] = -1e30f;
            }
        }

        // online softmax in base-2 (rows quad*4+r, spread over 16-lane groups)
#pragma unroll
        for (int r = 0; r < 4; ++r) {
            float mx = fmaxf(fmaxf(Sv[0][r], Sv[1][r]), fmaxf(Sv[2][r], Sv[3][r]));
#pragma unroll
            for (int d = 1; d < 16; d <<= 1) mx = fmaxf(mx, __shfl_xor(mx, d));
            float mo = mrow[r];
            float mn = fmaxf(mo, mx);
            float alpha = exp2f(mo - mn);
            float ps = 0.f;
#pragma unroll
            for (int kt = 0; kt < 4; ++kt) {
                float p = exp2f(Sv[kt][r] - mn);
                Sv[kt][r] = p;
                ps += p;
            }
#pragma unroll
            for (int d = 1; d < 16; d <<= 1) ps += __shfl_xor(ps, d);
            lrow[r] = lrow[r] * alpha + ps;
            mrow[r] = mn;
#pragma unroll
            for (int vt = 0; vt < 4; ++vt) Oacc[vt][r] *= alpha;
        }

        // P -> LDS (per-wave private rows; same-wave write->read ordered by lgkmcnt, no barrier)
#pragma unroll
        for (int kt = 0; kt < 4; ++kt)
#pragma unroll
            for (int r = 0; r < 4; ++r)
                Ps[(w * 16 + quad * 4 + r) * 72 + kt * 16 + l16] = f2bf(Sv[kt][r]);

        // O += P V
#pragma unroll
        for (int ks = 0; ks < 2; ++ks) {
            short8 ap = *(const short8*)&Ps[(w * 16 + l16) * 72 + ks * 32 + quad * 8];
#pragma unroll
            for (int vt = 0; vt < 4; ++vt) {
                short8 bv = *(const short8*)&Vt[(vt * 16 + l16) * 72 + ks * 32 + quad * 8];
                Oacc[vt] = __builtin_amdgcn_mfma_f32_16x16x32_bf16(ap, bv, Oacc[vt], 0, 0, 0);
            }
        }
    }

    // epilogue
#pragma unroll
    for (int vt = 0; vt < 4; ++vt)
#pragma unroll
        for (int r = 0; r < 4; ++r) {
            int row = q0 + w * 16 + quad * 4 + r;
            int col = h * DH + vt * 16 + l16;
            Cp[(size_t)(b * SEQ + row) * DIMN + col] = f2bf(Oacc[vt][r] / lrow[r]);
        }
}

extern "C" void kernel_launch(void* const* d_in, const int* in_sizes, int n_in,
                              void* d_out, int out_size, void* d_ws, size_t ws_size,
                              hipStream_t stream) {
    const float* x_q = (const float*)d_in[0];
    const float* x_k = (const float*)d_in[1];
    const float* x_v = (const float*)d_in[2];
    const int*   msk = (const int*)d_in[3];
    const float* q_w = (const float*)d_in[4];
    const float* q_b = (const float*)d_in[5];
    const float* k_w = (const float*)d_in[6];
    const float* k_b = (const float*)d_in[7];
    const float* v_w = (const float*)d_in[8];
    const float* v_b = (const float*)d_in[9];
    const float* o_w = (const float*)d_in[10];
    const float* o_b = (const float*)d_in[11];
    float* out = (float*)d_out;

    const size_t NEL = (size_t)BSZ * SEQ * DIMN;        // 4 Mi elements
    const size_t WEL = (size_t)DIMN * DIMN;             // 1 Mi elements
    ushort_t* Qp = (ushort_t*)d_ws;
    ushort_t* Kp = Qp + NEL;
    ushort_t* Vp = Kp + NEL;
    ushort_t* Cp = Vp + NEL;                            // 32 MB so far
    ushort_t* Wq = Cp + NEL;                            // +8 MB for bf16 weights
    ushort_t* Wk = Wq + WEL;
    ushort_t* Wv = Wk + WEL;
    ushort_t* Wo = Wv + WEL;
    const bool cvtW = ws_size >= (4 * NEL + 4 * WEL) * sizeof(ushort_t);

    dim3 gqkv(DIMN / 128, (BSZ * SEQ) / 64, 3);   // (8, 64, 3)
    dim3 go(DIMN / 128, (BSZ * SEQ) / 64);        // (8, 64)
    dim3 ga(BSZ * NH, SEQ / 64);                  // (32, 32)

    if (cvtW) {
        cvt_w<<<dim3(WEL / 1024, 4), 256, 0, stream>>>(q_w, k_w, v_w, o_w, Wq, Wk, Wv, Wo);
        gemm_qkv<true><<<gqkv, 256, 0, stream>>>(x_q, x_k, x_v, Wq, Wk, Wv,
                                                 q_b, k_b, v_b, Qp, Kp, Vp);
        attn_kernel<<<ga, 256, 0, stream>>>(Qp, Kp, Vp, msk, Cp);
        gemm_o<true><<<go, 256, 0, stream>>>(Cp, Wo, o_b, out);
    } else {
        gemm_qkv<false><<<gqkv, 256, 0, stream>>>(x_q, x_k, x_v, q_w, k_w, v_w,
                                                  q_b, k_b, v_b, Qp, Kp, Vp);
        attn_kernel<<<ga, 256, 0, stream>>>(Qp, Kp, Vp, msk, Cp);
        gemm_o<false><<<go, 256, 0, stream>>>(Cp, o_w, o_b, out);
    }
}

// Round 5
// 322.143 us; speedup vs baseline: 1.4607x; 1.0718x over previous
//
#include <hip/hip_runtime.h>

#define BSZ 2
#define SEQ 2048
#define DIMN 1024
#define NH 16
#define DH 64
#define LOG2E 1.4426950408889634f

typedef unsigned short ushort_t;
typedef __attribute__((ext_vector_type(8))) short short8;
typedef __attribute__((ext_vector_type(4))) short short4v;
typedef __attribute__((ext_vector_type(4))) float float4v;

__device__ __forceinline__ ushort_t f2bf(float f) {
    union { float f; unsigned int u; } c; c.f = f;
    return (ushort_t)((c.u + 0x8000u) >> 16);
}

__device__ __forceinline__ void async_cp16(const ushort_t* g, ushort_t* l) {
    __builtin_amdgcn_global_load_lds((const __attribute__((address_space(1))) void*)g,
                                     (__attribute__((address_space(3))) void*)l, 16, 0, 0);
}

// ---------------- weight pre-convert f32 -> bf16 (4 weight matrices) ----------------
__global__ __launch_bounds__(256) void cvt_w(
    const float* __restrict__ w0, const float* __restrict__ w1,
    const float* __restrict__ w2, const float* __restrict__ w3,
    ushort_t* __restrict__ o0, ushort_t* __restrict__ o1,
    ushort_t* __restrict__ o2, ushort_t* __restrict__ o3)
{
    const float* s; ushort_t* d;
    switch (blockIdx.y) {
        case 0: s = w0; d = o0; break;
        case 1: s = w1; d = o1; break;
        case 2: s = w2; d = o2; break;
        default: s = w3; d = o3; break;
    }
    int i = (blockIdx.x * 256 + threadIdx.x) * 4;
    float4v v = *(const float4v*)(s + i);
    short4v o;
#pragma unroll
    for (int j = 0; j < 4; ++j) o[j] = (short)f2bf(v[j]);
    *(short4v*)(d + i) = o;
}

// ---------------- fused QKV GEMM: tile 128x128, BK=32, m97 structure ----------------
// A = f32 activations (reg-staged + cvt, padded As); W = bf16 (async) or f32 (fallback).
// N axis = 3072: [0,1024) Q (scaled into log2 domain), [1024,2048) K, [2048,3072) V^T out.
template<bool WB>
__global__ __launch_bounds__(256) void gemm_qkv(
    const float* __restrict__ xq, const float* __restrict__ xk, const float* __restrict__ xv,
    const void* __restrict__ Wq, const void* __restrict__ Wk, const void* __restrict__ Wv,
    const float* __restrict__ qb, const float* __restrict__ kb, const float* __restrict__ vb,
    ushort_t* __restrict__ Qp, ushort_t* __restrict__ Kp, ushort_t* __restrict__ VpT)
{
    __shared__ ushort_t As[128 * 40];   // padded: 20 dw stride, conflict-free frag reads
    __shared__ ushort_t Bs[128 * 32];   // unpadded: async-contiguous
    const int tid  = threadIdx.x;
    const int lane = tid & 63;
    const int w    = tid >> 6;
    const int wm   = w >> 1, wn = w & 1;
    const int quad = lane >> 4;
    const int l16  = lane & 15;
    const int mBase = blockIdx.y * 128;
    const int nGlob = blockIdx.x * 128;
    const int z     = nGlob >> 10;         // 0=Q 1=K 2=V (block never straddles)
    const int nBase = nGlob & 1023;
    const float* A    = (z == 0) ? xq : (z == 1) ? xk : xv;
    const void*  W    = (z == 0) ? Wq : (z == 1) ? Wk : Wv;
    const float* bias = (z == 0) ? qb : (z == 1) ? kb : vb;

    float4v acc[4][4];
    const float4v z4 = {0.f, 0.f, 0.f, 0.f};
#pragma unroll
    for (int i = 0; i < 4; ++i)
#pragma unroll
        for (int j = 0; j < 4; ++j) acc[i][j] = z4;

    for (int k0 = 0; k0 < 1024; k0 += 32) {
        // prefetch A (f32) into regs before the barrier
        float4v a0[2], a1[2];
        float4v wf0[2], wf1[2];
#pragma unroll
        for (int it = 0; it < 2; ++it) {
            int c = it * 256 + tid, row = c >> 2, col = (c & 3) * 8;
            const float* g = A + (size_t)(mBase + row) * 1024 + k0 + col;
            a0[it] = *(const float4v*)g; a1[it] = *(const float4v*)(g + 4);
            if (!WB) {
                const float* gw = (const float*)W + (size_t)(nBase + row) * 1024 + k0 + col;
                wf0[it] = *(const float4v*)gw; wf1[it] = *(const float4v*)(gw + 4);
            }
        }
        __syncthreads();   // prev-tile frag reads done
#pragma unroll
        for (int it = 0; it < 2; ++it) {
            int c = it * 256 + tid, row = c >> 2, col = (c & 3) * 8;
            if (WB) {
                async_cp16((const ushort_t*)W + (size_t)(nBase + row) * 1024 + k0 + col, &Bs[c * 8]);
            } else {
                short8 sw;
#pragma unroll
                for (int j = 0; j < 8; ++j) sw[j] = (short)f2bf(j < 4 ? wf0[it][j] : wf1[it][j - 4]);
                *(short8*)&Bs[c * 8] = sw;
            }
            short8 sa;
#pragma unroll
            for (int j = 0; j < 8; ++j) sa[j] = (short)f2bf(j < 4 ? a0[it][j] : a1[it][j - 4]);
            *(short8*)&As[row * 40 + col] = sa;
        }
        __syncthreads();   // staging (incl. async) visible

        short8 af[4], bf[4];
#pragma unroll
        for (int mt = 0; mt < 4; ++mt)
            af[mt] = *(const short8*)&As[(wm * 64 + mt * 16 + l16) * 40 + quad * 8];
#pragma unroll
        for (int nt = 0; nt < 4; ++nt)
            bf[nt] = *(const short8*)&Bs[(wn * 64 + nt * 16 + l16) * 32 + quad * 8];
#pragma unroll
        for (int mt = 0; mt < 4; ++mt)
#pragma unroll
            for (int nt = 0; nt < 4; ++nt)
                acc[mt][nt] = __builtin_amdgcn_mfma_f32_16x16x32_bf16(af[mt], bf[nt], acc[mt][nt], 0, 0, 0);
    }

    const float scale = (z == 0) ? 0.125f * LOG2E : 1.0f;
    if (z < 2) {
        ushort_t* C = (z == 0) ? Qp : Kp;
#pragma unroll
        for (int mt = 0; mt < 4; ++mt)
#pragma unroll
            for (int nt = 0; nt < 4; ++nt) {
                int colg = nBase + wn * 64 + nt * 16 + l16;
                float bv = bias[colg];
#pragma unroll
                for (int r = 0; r < 4; ++r) {
                    int rowg = mBase + wm * 64 + mt * 16 + quad * 4 + r;
                    C[(size_t)rowg * 1024 + colg] = f2bf((acc[mt][nt][r] + bv) * scale);
                }
            }
    } else {
        // V: write transposed  VpT[(b*16+h)*64 + d][s], 4 consecutive s per lane -> 8B store
#pragma unroll
        for (int mt = 0; mt < 4; ++mt)
#pragma unroll
            for (int nt = 0; nt < 4; ++nt) {
                int n = nBase + wn * 64 + nt * 16 + l16;   // 0..1023 within V
                int hh = n >> 6, d = n & 63;
                float bv = bias[n];
                int rowg = mBase + wm * 64 + mt * 16 + quad * 4;
                int b = rowg >> 11, s = rowg & 2047;
                short4v pack;
#pragma unroll
                for (int r = 0; r < 4; ++r) pack[r] = (short)f2bf(acc[mt][nt][r] + bv);
                *(short4v*)&VpT[(((size_t)(b * 16 + hh) * 64 + d) << 11) + s] = pack;
            }
    }
}

// ---------------- O GEMM: tile 128x128, both operands bf16 via async ----------------
template<bool WB>
__global__ __launch_bounds__(256) void gemm_o(
    const ushort_t* __restrict__ A, const void* __restrict__ W,
    const float* __restrict__ bias, float* __restrict__ C)
{
    __shared__ ushort_t As[128 * 32];
    __shared__ ushort_t Bs[128 * 32];
    const int tid  = threadIdx.x;
    const int lane = tid & 63;
    const int w    = tid >> 6;
    const int wm   = w >> 1, wn = w & 1;
    const int quad = lane >> 4;
    const int l16  = lane & 15;
    const int mBase = blockIdx.y * 128;
    const int nBase = blockIdx.x * 128;

    float4v acc[4][4];
    const float4v z4 = {0.f, 0.f, 0.f, 0.f};
#pragma unroll
    for (int i = 0; i < 4; ++i)
#pragma unroll
        for (int j = 0; j < 4; ++j) acc[i][j] = z4;

    for (int k0 = 0; k0 < 1024; k0 += 32) {
        float4v wf0[2], wf1[2];
        if (!WB) {
#pragma unroll
            for (int it = 0; it < 2; ++it) {
                int c = it * 256 + tid, row = c >> 2, col = (c & 3) * 8;
                const float* gw = (const float*)W + (size_t)(nBase + row) * 1024 + k0 + col;
                wf0[it] = *(const float4v*)gw; wf1[it] = *(const float4v*)(gw + 4);
            }
        }
        __syncthreads();
#pragma unroll
        for (int it = 0; it < 2; ++it) {
            int c = it * 256 + tid, row = c >> 2, col = (c & 3) * 8;
            async_cp16(A + (size_t)(mBase + row) * 1024 + k0 + col, &As[c * 8]);
            if (WB) {
                async_cp16((const ushort_t*)W + (size_t)(nBase + row) * 1024 + k0 + col, &Bs[c * 8]);
            } else {
                short8 sw;
#pragma unroll
                for (int j = 0; j < 8; ++j) sw[j] = (short)f2bf(j < 4 ? wf0[it][j] : wf1[it][j - 4]);
                *(short8*)&Bs[c * 8] = sw;
            }
        }
        __syncthreads();

        short8 af[4], bf[4];
#pragma unroll
        for (int mt = 0; mt < 4; ++mt)
            af[mt] = *(const short8*)&As[(wm * 64 + mt * 16 + l16) * 32 + quad * 8];
#pragma unroll
        for (int nt = 0; nt < 4; ++nt)
            bf[nt] = *(const short8*)&Bs[(wn * 64 + nt * 16 + l16) * 32 + quad * 8];
#pragma unroll
        for (int mt = 0; mt < 4; ++mt)
#pragma unroll
            for (int nt = 0; nt < 4; ++nt)
                acc[mt][nt] = __builtin_amdgcn_mfma_f32_16x16x32_bf16(af[mt], bf[nt], acc[mt][nt], 0, 0, 0);
    }

#pragma unroll
    for (int mt = 0; mt < 4; ++mt)
#pragma unroll
        for (int nt = 0; nt < 4; ++nt) {
            int colg = nBase + wn * 64 + nt * 16 + l16;
            float bv = bias[colg];
#pragma unroll
            for (int r = 0; r < 4; ++r) {
                int rowg = mBase + wm * 64 + mt * 16 + quad * 4 + r;
                C[(size_t)rowg * 1024 + colg] = acc[mt][nt][r] + bv;
            }
        }
}

// ---------------- fused flash attention: Q-tile 64, K-tile 64, V pre-transposed ----
__global__ __launch_bounds__(256) void attn_kernel(
    const ushort_t* __restrict__ Qp, const ushort_t* __restrict__ Kp,
    const ushort_t* __restrict__ VpT, const int* __restrict__ mask,
    ushort_t* __restrict__ Cp)
{
    __shared__ ushort_t Qs[64 * 72];
    __shared__ ushort_t Ks[64 * 72];
    __shared__ ushort_t Vt[64 * 72];   // [dim][key]
    __shared__ ushort_t Ps[64 * 72];

    const int tid  = threadIdx.x;
    const int lane = tid & 63;
    const int w    = tid >> 6;
    const int quad = lane >> 4;
    const int l16  = lane & 15;
    const int b    = blockIdx.x >> 4;
    const int h    = blockIdx.x & 15;
    const int q0   = blockIdx.y * 64;

    short8 qreg[2];
#pragma unroll
    for (int it = 0; it < 2; ++it) {
        int c = it * 256 + tid, row = c >> 3, col = (c & 7) * 8;
        qreg[it] = *(const short8*)(Qp + (size_t)(b * SEQ + q0 + row) * DIMN + h * DH + col);
    }
#pragma unroll
    for (int it = 0; it < 2; ++it) {
        int c = it * 256 + tid, row = c >> 3, col = (c & 7) * 8;
        *(short8*)&Qs[row * 72 + col] = qreg[it];
    }

    const float4v z4 = {0.f, 0.f, 0.f, 0.f};
    float4v Oacc[4];
#pragma unroll
    for (int vt = 0; vt < 4; ++vt) Oacc[vt] = z4;
    float4v Lacc = z4;
    float mrow[4];
#pragma unroll
    for (int r = 0; r < 4; ++r) mrow[r] = -3e38f;

    short8 ones;
#pragma unroll
    for (int j = 0; j < 8; ++j) ones[j] = (short)0x3F80;   // bf16 1.0

    const ushort_t* Vbase = VpT + ((size_t)(b * 16 + h) * 64) * 2048;

    for (int kt0 = 0; kt0 < SEQ; kt0 += 64) {
        short8 kreg[2], vreg[2];
#pragma unroll
        for (int it = 0; it < 2; ++it) {
            int c = it * 256 + tid, row = c >> 3, col = (c & 7) * 8;
            kreg[it] = *(const short8*)(Kp + (size_t)(b * SEQ + kt0 + row) * DIMN + h * DH + col);
            vreg[it] = *(const short8*)(Vbase + (size_t)row * 2048 + kt0 + col);
        }
        __syncthreads();   // prev-iter LDS reads done
#pragma unroll
        for (int it = 0; it < 2; ++it) {
            int c = it * 256 + tid, row = c >> 3, col = (c & 7) * 8;
            *(short8*)&Ks[row * 72 + col] = kreg[it];
            *(short8*)&Vt[row * 72 + col] = vreg[it];
        }
        __syncthreads();   // staging visible

        // S = Q K^T (log2 domain; Q pre-scaled)
        float4v Sv[4];
#pragma unroll
        for (int kt = 0; kt < 4; ++kt) Sv[kt] = z4;
#pragma unroll
        for (int ks = 0; ks < 2; ++ks) {
            short8 aq = *(const short8*)&Qs[(w * 16 + l16) * 72 + ks * 32 + quad * 8];
#pragma unroll
            for (int kt = 0; kt < 4; ++kt) {
                short8 bk = *(const short8*)&Ks[(kt * 16 + l16) * 72 + ks * 32 + quad * 8];
                Sv[kt] = __builtin_amdgcn_mfma_f32_16x16x32_bf16(aq, bk, Sv[kt], 0, 0, 0);
            }
        }

        // additive mask
#pragma unroll
        for (int kt = 0; kt < 4; ++kt) {
            float madd = (mask[b * SEQ + kt0 + kt * 16 + l16] == 0) ? -1e30f : 0.0f;
#pragma unroll
            for (int r = 0; r < 4; ++r) Sv[kt][r] += madd;
        }

        // online softmax (base-2); sums deferred to MFMA (Lacc)
#pragma unroll
        for (int r = 0; r < 4; ++r) {
            float mx = fmaxf(fmaxf(Sv[0][r], Sv[1][r]), fmaxf(Sv[2][r], Sv[3][r]));
#pragma unroll
            for (int d = 1; d < 16; d <<= 1) mx = fmaxf(mx, __shfl_xor(mx, d));
            float mo = mrow[r];
            float mn = fmaxf(mo, mx);
            float alpha = exp2f(mo - mn);
            mrow[r] = mn;
#pragma unroll
            for (int kt = 0; kt < 4; ++kt) Sv[kt][r] = exp2f(Sv[kt][r] - mn);
#pragma unroll
            for (int vt = 0; vt < 4; ++vt) Oacc[vt][r] *= alpha;
            Lacc[r] *= alpha;
        }

        // P -> LDS (per-wave private rows; same-wave ordering via lgkmcnt)
#pragma unroll
        for (int kt = 0; kt < 4; ++kt)
#pragma unroll
            for (int r = 0; r < 4; ++r)
                Ps[(w * 16 + quad * 4 + r) * 72 + kt * 16 + l16] = f2bf(Sv[kt][r]);

        // O += P V ; L += P 1
#pragma unroll
        for (int ks = 0; ks < 2; ++ks) {
            short8 ap = *(const short8*)&Ps[(w * 16 + l16) * 72 + ks * 32 + quad * 8];
            Lacc = __builtin_amdgcn_mfma_f32_16x16x32_bf16(ap, ones, Lacc, 0, 0, 0);
#pragma unroll
            for (int vt = 0; vt < 4; ++vt) {
                short8 bv = *(const short8*)&Vt[(vt * 16 + l16) * 72 + ks * 32 + quad * 8];
                Oacc[vt] = __builtin_amdgcn_mfma_f32_16x16x32_bf16(ap, bv, Oacc[vt], 0, 0, 0);
            }
        }
    }

    float inv[4];
#pragma unroll
    for (int r = 0; r < 4; ++r) inv[r] = 1.0f / Lacc[r];
#pragma unroll
    for (int vt = 0; vt < 4; ++vt)
#pragma unroll
        for (int r = 0; r < 4; ++r) {
            int row = q0 + w * 16 + quad * 4 + r;
            int col = h * DH + vt * 16 + l16;
            Cp[(size_t)(b * SEQ + row) * DIMN + col] = f2bf(Oacc[vt][r] * inv[r]);
        }
}

extern "C" void kernel_launch(void* const* d_in, const int* in_sizes, int n_in,
                              void* d_out, int out_size, void* d_ws, size_t ws_size,
                              hipStream_t stream) {
    const float* x_q = (const float*)d_in[0];
    const float* x_k = (const float*)d_in[1];
    const float* x_v = (const float*)d_in[2];
    const int*   msk = (const int*)d_in[3];
    const float* q_w = (const float*)d_in[4];
    const float* q_b = (const float*)d_in[5];
    const float* k_w = (const float*)d_in[6];
    const float* k_b = (const float*)d_in[7];
    const float* v_w = (const float*)d_in[8];
    const float* v_b = (const float*)d_in[9];
    const float* o_w = (const float*)d_in[10];
    const float* o_b = (const float*)d_in[11];
    float* out = (float*)d_out;

    const size_t NEL = (size_t)BSZ * SEQ * DIMN;
    const size_t WEL = (size_t)DIMN * DIMN;
    ushort_t* Qp  = (ushort_t*)d_ws;
    ushort_t* Kp  = Qp + NEL;
    ushort_t* VpT = Kp + NEL;
    ushort_t* Cp  = VpT + NEL;
    ushort_t* Wq  = Cp + NEL;
    ushort_t* Wk  = Wq + WEL;
    ushort_t* Wv  = Wk + WEL;
    ushort_t* Wo  = Wv + WEL;
    const bool cvtW = ws_size >= (4 * NEL + 4 * WEL) * sizeof(ushort_t);

    dim3 gqkv(3 * DIMN / 128, (BSZ * SEQ) / 128);  // (24, 32)
    dim3 go(DIMN / 128, (BSZ * SEQ) / 128);        // (8, 32)
    dim3 ga(BSZ * NH, SEQ / 64);                   // (32, 32)

    if (cvtW) {
        cvt_w<<<dim3(WEL / 1024, 4), 256, 0, stream>>>(q_w, k_w, v_w, o_w, Wq, Wk, Wv, Wo);
        gemm_qkv<true><<<gqkv, 256, 0, stream>>>(x_q, x_k, x_v, Wq, Wk, Wv,
                                                 q_b, k_b, v_b, Qp, Kp, VpT);
        attn_kernel<<<ga, 256, 0, stream>>>(Qp, Kp, VpT, msk, Cp);
        gemm_o<true><<<go, 256, 0, stream>>>(Cp, Wo, o_b, out);
    } else {
        gemm_qkv<false><<<gqkv, 256, 0, stream>>>(x_q, x_k, x_v, q_w, k_w, v_w,
                                                  q_b, k_b, v_b, Qp, Kp, VpT);
        attn_kernel<<<ga, 256, 0, stream>>>(Qp, Kp, VpT, msk, Cp);
        gemm_o<false><<<go, 256, 0, stream>>>(Cp, o_w, o_b, out);
    }
}

// Round 6
// 285.518 us; speedup vs baseline: 1.6481x; 1.1283x over previous
//
#include <hip/hip_runtime.h>
#include <hip/hip_bf16.h>

#define BSZ 2
#define SEQ 2048
#define DIMN 1024
#define NH 16
#define DH 64
#define LOG2E 1.4426950408889634f

typedef unsigned short ushort_t;
typedef __attribute__((ext_vector_type(8))) short short8;
typedef __attribute__((ext_vector_type(4))) short short4v;
typedef __attribute__((ext_vector_type(4))) float float4v;

__device__ __forceinline__ ushort_t f2bf(float f) {
    union { float f; unsigned int u; } c; c.f = f;
    return (ushort_t)((c.u + 0x8000u) >> 16);
}
// packed 2xf32 -> 2xbf16 (v_cvt_pk_bf16_f32 via hip_bf16)
__device__ __forceinline__ unsigned int pkbf(float a, float b) {
    __hip_bfloat162 h = __float22bfloat162_rn(make_float2(a, b));
    unsigned int u; __builtin_memcpy(&u, &h, 4); return u;
}
__device__ __forceinline__ void async_cp16(const ushort_t* g, ushort_t* l) {
    __builtin_amdgcn_global_load_lds((const __attribute__((address_space(1))) void*)g,
                                     (__attribute__((address_space(3))) void*)l, 16, 0, 0);
}

// ---------------- pre-convert f32 -> bf16: 3 activations (4M) + 4 weights (1M) ------
__global__ __launch_bounds__(256) void cvt_all(
    const float* __restrict__ x0, const float* __restrict__ x1, const float* __restrict__ x2,
    const float* __restrict__ w0, const float* __restrict__ w1,
    const float* __restrict__ w2, const float* __restrict__ w3,
    ushort_t* __restrict__ dx0, ushort_t* __restrict__ dx1, ushort_t* __restrict__ dx2,
    ushort_t* __restrict__ dw0, ushort_t* __restrict__ dw1,
    ushort_t* __restrict__ dw2, ushort_t* __restrict__ dw3)
{
    const float* s; ushort_t* d; int nblk;
    switch (blockIdx.y) {
        case 0: s = x0; d = dx0; nblk = 4096; break;
        case 1: s = x1; d = dx1; nblk = 4096; break;
        case 2: s = x2; d = dx2; nblk = 4096; break;
        case 3: s = w0; d = dw0; nblk = 1024; break;
        case 4: s = w1; d = dw1; nblk = 1024; break;
        case 5: s = w2; d = dw2; nblk = 1024; break;
        default: s = w3; d = dw3; nblk = 1024; break;
    }
    if ((int)blockIdx.x >= nblk) return;
    int i = (blockIdx.x * 256 + threadIdx.x) * 4;
    float4v v = *(const float4v*)(s + i);
    short4v o;
#pragma unroll
    for (int j = 0; j < 4; ++j) o[j] = (short)f2bf(v[j]);
    *(short4v*)(d + i) = o;
}

// ---------------- tier-2 QKV GEMM: pure bf16, m97 async/async, 128x128, BK=32 -------
__global__ __launch_bounds__(256) void gemm_qkv2(
    const ushort_t* __restrict__ Xq, const ushort_t* __restrict__ Xk, const ushort_t* __restrict__ Xv,
    const ushort_t* __restrict__ Wq, const ushort_t* __restrict__ Wk, const ushort_t* __restrict__ Wv,
    const float* __restrict__ qb, const float* __restrict__ kb, const float* __restrict__ vb,
    ushort_t* __restrict__ Qp, ushort_t* __restrict__ Kp, ushort_t* __restrict__ VpT)
{
    __shared__ ushort_t As[128 * 32];
    __shared__ ushort_t Bs[128 * 32];
    const int tid  = threadIdx.x;
    const int lane = tid & 63;
    const int w    = tid >> 6;
    const int wm   = w >> 1, wn = w & 1;
    const int quad = lane >> 4;
    const int l16  = lane & 15;
    const int mBase = blockIdx.y * 128;
    const int nGlob = blockIdx.x * 128;
    const int z     = nGlob >> 10;
    const int nBase = nGlob & 1023;
    const ushort_t* A    = (z == 0) ? Xq : (z == 1) ? Xk : Xv;
    const ushort_t* W    = (z == 0) ? Wq : (z == 1) ? Wk : Wv;
    const float*    bias = (z == 0) ? qb : (z == 1) ? kb : vb;

    float4v acc[4][4];
    const float4v z4 = {0.f, 0.f, 0.f, 0.f};
#pragma unroll
    for (int i = 0; i < 4; ++i)
#pragma unroll
        for (int j = 0; j < 4; ++j) acc[i][j] = z4;

    for (int k0 = 0; k0 < 1024; k0 += 32) {
        __syncthreads();
#pragma unroll
        for (int it = 0; it < 2; ++it) {
            int c = it * 256 + tid, row = c >> 2, col = (c & 3) * 8;
            async_cp16(A + (size_t)(mBase + row) * 1024 + k0 + col, &As[c * 8]);
            async_cp16(W + (size_t)(nBase + row) * 1024 + k0 + col, &Bs[c * 8]);
        }
        __syncthreads();

        short8 af[4], bf[4];
#pragma unroll
        for (int mt = 0; mt < 4; ++mt)
            af[mt] = *(const short8*)&As[(wm * 64 + mt * 16 + l16) * 32 + quad * 8];
#pragma unroll
        for (int nt = 0; nt < 4; ++nt)
            bf[nt] = *(const short8*)&Bs[(wn * 64 + nt * 16 + l16) * 32 + quad * 8];
#pragma unroll
        for (int mt = 0; mt < 4; ++mt)
#pragma unroll
            for (int nt = 0; nt < 4; ++nt)
                acc[mt][nt] = __builtin_amdgcn_mfma_f32_16x16x32_bf16(af[mt], bf[nt], acc[mt][nt], 0, 0, 0);
    }

    const float scale = (z == 0) ? 0.125f * LOG2E : 1.0f;
    if (z < 2) {
        ushort_t* C = (z == 0) ? Qp : Kp;
#pragma unroll
        for (int mt = 0; mt < 4; ++mt)
#pragma unroll
            for (int nt = 0; nt < 4; ++nt) {
                int colg = nBase + wn * 64 + nt * 16 + l16;
                float bv = bias[colg];
#pragma unroll
                for (int r = 0; r < 4; ++r) {
                    int rowg = mBase + wm * 64 + mt * 16 + quad * 4 + r;
                    C[(size_t)rowg * 1024 + colg] = f2bf((acc[mt][nt][r] + bv) * scale);
                }
            }
    } else {
#pragma unroll
        for (int mt = 0; mt < 4; ++mt)
#pragma unroll
            for (int nt = 0; nt < 4; ++nt) {
                int n = nBase + wn * 64 + nt * 16 + l16;
                int hh = n >> 6, d = n & 63;
                float bv = bias[n];
                int rowg = mBase + wm * 64 + mt * 16 + quad * 4;
                int b = rowg >> 11, s = rowg & 2047;
                short4v pack;
#pragma unroll
                for (int r = 0; r < 4; ++r) pack[r] = (short)f2bf(acc[mt][nt][r] + bv);
                *(short4v*)&VpT[(((size_t)(b * 16 + hh) * 64 + d) << 11) + s] = pack;
            }
    }
}

// ---------------- tier-0 fallback QKV GEMM (f32 A + f32 W, reg-staged) --------------
__global__ __launch_bounds__(256) void gemm_qkv0(
    const float* __restrict__ xq, const float* __restrict__ xk, const float* __restrict__ xv,
    const float* __restrict__ Wqf, const float* __restrict__ Wkf, const float* __restrict__ Wvf,
    const float* __restrict__ qb, const float* __restrict__ kb, const float* __restrict__ vb,
    ushort_t* __restrict__ Qp, ushort_t* __restrict__ Kp, ushort_t* __restrict__ VpT)
{
    __shared__ ushort_t As[128 * 40];
    __shared__ ushort_t Bs[128 * 32];
    const int tid  = threadIdx.x;
    const int lane = tid & 63;
    const int w    = tid >> 6;
    const int wm   = w >> 1, wn = w & 1;
    const int quad = lane >> 4;
    const int l16  = lane & 15;
    const int mBase = blockIdx.y * 128;
    const int nGlob = blockIdx.x * 128;
    const int z     = nGlob >> 10;
    const int nBase = nGlob & 1023;
    const float* A    = (z == 0) ? xq : (z == 1) ? xk : xv;
    const float* W    = (z == 0) ? Wqf : (z == 1) ? Wkf : Wvf;
    const float* bias = (z == 0) ? qb : (z == 1) ? kb : vb;

    float4v acc[4][4];
    const float4v z4 = {0.f, 0.f, 0.f, 0.f};
#pragma unroll
    for (int i = 0; i < 4; ++i)
#pragma unroll
        for (int j = 0; j < 4; ++j) acc[i][j] = z4;

    for (int k0 = 0; k0 < 1024; k0 += 32) {
        float4v a0[2], a1[2], wf0[2], wf1[2];
#pragma unroll
        for (int it = 0; it < 2; ++it) {
            int c = it * 256 + tid, row = c >> 2, col = (c & 3) * 8;
            const float* g = A + (size_t)(mBase + row) * 1024 + k0 + col;
            a0[it] = *(const float4v*)g; a1[it] = *(const float4v*)(g + 4);
            const float* gw = W + (size_t)(nBase + row) * 1024 + k0 + col;
            wf0[it] = *(const float4v*)gw; wf1[it] = *(const float4v*)(gw + 4);
        }
        __syncthreads();
#pragma unroll
        for (int it = 0; it < 2; ++it) {
            int c = it * 256 + tid, row = c >> 2, col = (c & 3) * 8;
            short8 sa, sw;
#pragma unroll
            for (int j = 0; j < 8; ++j) {
                sa[j] = (short)f2bf(j < 4 ? a0[it][j] : a1[it][j - 4]);
                sw[j] = (short)f2bf(j < 4 ? wf0[it][j] : wf1[it][j - 4]);
            }
            *(short8*)&As[row * 40 + col] = sa;
            *(short8*)&Bs[c * 8] = sw;
        }
        __syncthreads();

        short8 af[4], bf[4];
#pragma unroll
        for (int mt = 0; mt < 4; ++mt)
            af[mt] = *(const short8*)&As[(wm * 64 + mt * 16 + l16) * 40 + quad * 8];
#pragma unroll
        for (int nt = 0; nt < 4; ++nt)
            bf[nt] = *(const short8*)&Bs[(wn * 64 + nt * 16 + l16) * 32 + quad * 8];
#pragma unroll
        for (int mt = 0; mt < 4; ++mt)
#pragma unroll
            for (int nt = 0; nt < 4; ++nt)
                acc[mt][nt] = __builtin_amdgcn_mfma_f32_16x16x32_bf16(af[mt], bf[nt], acc[mt][nt], 0, 0, 0);
    }

    const float scale = (z == 0) ? 0.125f * LOG2E : 1.0f;
    if (z < 2) {
        ushort_t* C = (z == 0) ? Qp : Kp;
#pragma unroll
        for (int mt = 0; mt < 4; ++mt)
#pragma unroll
            for (int nt = 0; nt < 4; ++nt) {
                int colg = nBase + wn * 64 + nt * 16 + l16;
                float bv = bias[colg];
#pragma unroll
                for (int r = 0; r < 4; ++r) {
                    int rowg = mBase + wm * 64 + mt * 16 + quad * 4 + r;
                    C[(size_t)rowg * 1024 + colg] = f2bf((acc[mt][nt][r] + bv) * scale);
                }
            }
    } else {
#pragma unroll
        for (int mt = 0; mt < 4; ++mt)
#pragma unroll
            for (int nt = 0; nt < 4; ++nt) {
                int n = nBase + wn * 64 + nt * 16 + l16;
                int hh = n >> 6, d = n & 63;
                float bv = bias[n];
                int rowg = mBase + wm * 64 + mt * 16 + quad * 4;
                int b = rowg >> 11, s = rowg & 2047;
                short4v pack;
#pragma unroll
                for (int r = 0; r < 4; ++r) pack[r] = (short)f2bf(acc[mt][nt][r] + bv);
                *(short4v*)&VpT[(((size_t)(b * 16 + hh) * 64 + d) << 11) + s] = pack;
            }
    }
}

// ---------------- O GEMM: A bf16 async; W bf16 async (tier2) or f32 (tier0) ---------
template<bool WB>
__global__ __launch_bounds__(256) void gemm_o(
    const ushort_t* __restrict__ A, const void* __restrict__ W,
    const float* __restrict__ bias, float* __restrict__ C)
{
    __shared__ ushort_t As[128 * 32];
    __shared__ ushort_t Bs[128 * 32];
    const int tid  = threadIdx.x;
    const int lane = tid & 63;
    const int w    = tid >> 6;
    const int wm   = w >> 1, wn = w & 1;
    const int quad = lane >> 4;
    const int l16  = lane & 15;
    const int mBase = blockIdx.y * 128;
    const int nBase = blockIdx.x * 128;

    float4v acc[4][4];
    const float4v z4 = {0.f, 0.f, 0.f, 0.f};
#pragma unroll
    for (int i = 0; i < 4; ++i)
#pragma unroll
        for (int j = 0; j < 4; ++j) acc[i][j] = z4;

    for (int k0 = 0; k0 < 1024; k0 += 32) {
        float4v wf0[2], wf1[2];
        if (!WB) {
#pragma unroll
            for (int it = 0; it < 2; ++it) {
                int c = it * 256 + tid, row = c >> 2, col = (c & 3) * 8;
                const float* gw = (const float*)W + (size_t)(nBase + row) * 1024 + k0 + col;
                wf0[it] = *(const float4v*)gw; wf1[it] = *(const float4v*)(gw + 4);
            }
        }
        __syncthreads();
#pragma unroll
        for (int it = 0; it < 2; ++it) {
            int c = it * 256 + tid, row = c >> 2, col = (c & 3) * 8;
            async_cp16(A + (size_t)(mBase + row) * 1024 + k0 + col, &As[c * 8]);
            if (WB) {
                async_cp16((const ushort_t*)W + (size_t)(nBase + row) * 1024 + k0 + col, &Bs[c * 8]);
            } else {
                short8 sw;
#pragma unroll
                for (int j = 0; j < 8; ++j) sw[j] = (short)f2bf(j < 4 ? wf0[it][j] : wf1[it][j - 4]);
                *(short8*)&Bs[c * 8] = sw;
            }
        }
        __syncthreads();

        short8 af[4], bf[4];
#pragma unroll
        for (int mt = 0; mt < 4; ++mt)
            af[mt] = *(const short8*)&As[(wm * 64 + mt * 16 + l16) * 32 + quad * 8];
#pragma unroll
        for (int nt = 0; nt < 4; ++nt)
            bf[nt] = *(const short8*)&Bs[(wn * 64 + nt * 16 + l16) * 32 + quad * 8];
#pragma unroll
        for (int mt = 0; mt < 4; ++mt)
#pragma unroll
            for (int nt = 0; nt < 4; ++nt)
                acc[mt][nt] = __builtin_amdgcn_mfma_f32_16x16x32_bf16(af[mt], bf[nt], acc[mt][nt], 0, 0, 0);
    }

#pragma unroll
    for (int mt = 0; mt < 4; ++mt)
#pragma unroll
        for (int nt = 0; nt < 4; ++nt) {
            int colg = nBase + wn * 64 + nt * 16 + l16;
            float bv = bias[colg];
#pragma unroll
            for (int r = 0; r < 4; ++r) {
                int rowg = mBase + wm * 64 + mt * 16 + quad * 4 + r;
                C[(size_t)rowg * 1024 + colg] = acc[mt][nt][r] + bv;
            }
        }
}

// ---------------- fused flash attention, S^T formulation -----------------------------
// S^T = K.Q^T  (m=key, n=qrow): per-thread softmax state is per-qrow (lane l16).
// P lands with 4 consecutive keys per reg quad -> packed b64 LDS writes.
// O^T = V^T.P^T ; L = 1.P^T.  Ps aliases the dead Qs buffer (LDS 27.6 KB).
__global__ __launch_bounds__(256) void attn_kernel(
    const ushort_t* __restrict__ Qp, const ushort_t* __restrict__ Kp,
    const ushort_t* __restrict__ VpT, const int* __restrict__ mask,
    ushort_t* __restrict__ Cp)
{
    __shared__ ushort_t QPs[64 * 72];  // Q staging, then reused as Ps
    __shared__ ushort_t Ks[64 * 72];
    __shared__ ushort_t Vt[64 * 72];   // [dim][key]

    const int tid  = threadIdx.x;
    const int lane = tid & 63;
    const int w    = tid >> 6;
    const int quad = lane >> 4;
    const int l16  = lane & 15;
    const int b    = blockIdx.x >> 4;
    const int h    = blockIdx.x & 15;
    const int q0   = blockIdx.y * 64;

    // stage Q (64x64), then hoist B-frags (Qs static across K-loop)
    {
        short8 qreg[2];
#pragma unroll
        for (int it = 0; it < 2; ++it) {
            int c = it * 256 + tid, row = c >> 3, col = (c & 7) * 8;
            qreg[it] = *(const short8*)(Qp + (size_t)(b * SEQ + q0 + row) * DIMN + h * DH + col);
        }
#pragma unroll
        for (int it = 0; it < 2; ++it) {
            int c = it * 256 + tid, row = c >> 3, col = (c & 7) * 8;
            *(short8*)&QPs[row * 72 + col] = qreg[it];
        }
    }
    __syncthreads();
    short8 bq[2];
#pragma unroll
    for (int ks = 0; ks < 2; ++ks)
        bq[ks] = *(const short8*)&QPs[(w * 16 + l16) * 72 + ks * 32 + quad * 8];

    const float4v z4 = {0.f, 0.f, 0.f, 0.f};
    float4v Oacc[4];   // O^T tiles: [dim vt*16+quad*4+r][qrow l16]
#pragma unroll
    for (int vt = 0; vt < 4; ++vt) Oacc[vt] = z4;
    float4v Lacc = z4;
    float mrow = -3e38f;

    short8 ones;
#pragma unroll
    for (int j = 0; j < 8; ++j) ones[j] = (short)0x3F80;

    const ushort_t* Vbase = VpT + ((size_t)(b * 16 + h) * 64) * 2048;

    for (int kt0 = 0; kt0 < SEQ; kt0 += 64) {
        // prefetch K tile, V^T tile, mask
        short8 kreg[2], vreg[2];
        int4 mv4[4];
#pragma unroll
        for (int it = 0; it < 2; ++it) {
            int c = it * 256 + tid, row = c >> 3, col = (c & 7) * 8;
            kreg[it] = *(const short8*)(Kp + (size_t)(b * SEQ + kt0 + row) * DIMN + h * DH + col);
            vreg[it] = *(const short8*)(Vbase + (size_t)row * 2048 + kt0 + col);
        }
#pragma unroll
        for (int kt = 0; kt < 4; ++kt)
            mv4[kt] = *(const int4*)(mask + b * SEQ + kt0 + kt * 16 + quad * 4);

        __syncthreads();   // prev-iter LDS reads complete (incl. Ps)
#pragma unroll
        for (int it = 0; it < 2; ++it) {
            int c = it * 256 + tid, row = c >> 3, col = (c & 7) * 8;
            *(short8*)&Ks[row * 72 + col] = kreg[it];
            *(short8*)&Vt[row * 72 + col] = vreg[it];
        }
        __syncthreads();   // staging visible

        // S^T = K.Q^T : m-tiles kt (keys), n = qrows of this wave
        float4v Sv[4];
#pragma unroll
        for (int kt = 0; kt < 4; ++kt) Sv[kt] = z4;
#pragma unroll
        for (int ks = 0; ks < 2; ++ks)
#pragma unroll
            for (int kt = 0; kt < 4; ++kt) {
                short8 ak = *(const short8*)&Ks[(kt * 16 + l16) * 72 + ks * 32 + quad * 8];
                Sv[kt] = __builtin_amdgcn_mfma_f32_16x16x32_bf16(ak, bq[ks], Sv[kt], 0, 0, 0);
            }

        // additive mask (key = kt*16 + quad*4 + r)
#pragma unroll
        for (int kt = 0; kt < 4; ++kt) {
            int4 mv = mv4[kt];
#pragma unroll
            for (int r = 0; r < 4; ++r) {
                int m = (r == 0) ? mv.x : (r == 1) ? mv.y : (r == 2) ? mv.z : mv.w;
                Sv[kt][r] += (m == 0) ? -1e30f : 0.0f;
            }
        }

        // online softmax (base-2), all 16 scores belong to qrow l16
        float mx = Sv[0][0];
#pragma unroll
        for (int kt = 0; kt < 4; ++kt)
#pragma unroll
            for (int r = 0; r < 4; ++r) mx = fmaxf(mx, Sv[kt][r]);
        mx = fmaxf(mx, __shfl_xor(mx, 16));
        mx = fmaxf(mx, __shfl_xor(mx, 32));
        float mn = fmaxf(mrow, mx);
        float alpha = exp2f(mrow - mn);
        mrow = mn;
#pragma unroll
        for (int kt = 0; kt < 4; ++kt)
#pragma unroll
            for (int r = 0; r < 4; ++r) Sv[kt][r] = exp2f(Sv[kt][r] - mn);
#pragma unroll
        for (int vt = 0; vt < 4; ++vt) Oacc[vt] *= alpha;
        Lacc *= alpha;

        // P -> Ps[qrow][key] packed b64 (4 consecutive keys per write)
#pragma unroll
        for (int kt = 0; kt < 4; ++kt) {
            uint2 pk;
            pk.x = pkbf(Sv[kt][0], Sv[kt][1]);
            pk.y = pkbf(Sv[kt][2], Sv[kt][3]);
            *(uint2*)&QPs[(w * 16 + l16) * 72 + kt * 16 + quad * 4] = pk;
        }

        // O^T += V^T.P^T ; L += 1.P^T  (same-wave Ps write->read, lgkmcnt-ordered)
#pragma unroll
        for (int ks = 0; ks < 2; ++ks) {
            short8 bp = *(const short8*)&QPs[(w * 16 + l16) * 72 + ks * 32 + quad * 8];
            Lacc = __builtin_amdgcn_mfma_f32_16x16x32_bf16(ones, bp, Lacc, 0, 0, 0);
#pragma unroll
            for (int vt = 0; vt < 4; ++vt) {
                short8 av = *(const short8*)&Vt[(vt * 16 + l16) * 72 + ks * 32 + quad * 8];
                Oacc[vt] = __builtin_amdgcn_mfma_f32_16x16x32_bf16(av, bp, Oacc[vt], 0, 0, 0);
            }
        }
    }

    // epilogue: O^T -> Cp[row=qrow][col=dim], packed 8B stores
    float inv = 1.0f / Lacc[0];
    int row = q0 + w * 16 + l16;
#pragma unroll
    for (int vt = 0; vt < 4; ++vt) {
        uint2 pk;
        pk.x = pkbf(Oacc[vt][0] * inv, Oacc[vt][1] * inv);
        pk.y = pkbf(Oacc[vt][2] * inv, Oacc[vt][3] * inv);
        *(uint2*)&Cp[(size_t)(b * SEQ + row) * DIMN + h * DH + vt * 16 + quad * 4] = pk;
    }
}

extern "C" void kernel_launch(void* const* d_in, const int* in_sizes, int n_in,
                              void* d_out, int out_size, void* d_ws, size_t ws_size,
                              hipStream_t stream) {
    const float* x_q = (const float*)d_in[0];
    const float* x_k = (const float*)d_in[1];
    const float* x_v = (const float*)d_in[2];
    const int*   msk = (const int*)d_in[3];
    const float* q_w = (const float*)d_in[4];
    const float* q_b = (const float*)d_in[5];
    const float* k_w = (const float*)d_in[6];
    const float* k_b = (const float*)d_in[7];
    const float* v_w = (const float*)d_in[8];
    const float* v_b = (const float*)d_in[9];
    const float* o_w = (const float*)d_in[10];
    const float* o_b = (const float*)d_in[11];
    float* out = (float*)d_out;

    const size_t NEL = (size_t)BSZ * SEQ * DIMN;   // 4 Mi
    const size_t WEL = (size_t)DIMN * DIMN;        // 1 Mi
    ushort_t* wsu = (ushort_t*)d_ws;

    dim3 gqkv(3 * DIMN / 128, (BSZ * SEQ) / 128);  // (24, 32)
    dim3 go(DIMN / 128, (BSZ * SEQ) / 128);        // (8, 32)
    dim3 ga(BSZ * NH, SEQ / 64);                   // (32, 32)

    if (ws_size >= (7 * NEL + 4 * WEL) * sizeof(ushort_t)) {
        // tier 2: Xq(=Cp later) Xk Xv | Qp Kp VpT | Wq Wk Wv Wo   (56 MB)
        ushort_t* Xq = wsu;
        ushort_t* Xk = Xq + NEL;
        ushort_t* Xv = Xk + NEL;
        ushort_t* Qp = Xv + NEL;
        ushort_t* Kp = Qp + NEL;
        ushort_t* VpT = Kp + NEL;
        ushort_t* Wq = VpT + NEL;
        ushort_t* Wk = Wq + WEL;
        ushort_t* Wv = Wk + WEL;
        ushort_t* Wo = Wv + WEL;
        ushort_t* Cp = Xq;   // alias: Xq dead after QKV GEMM

        cvt_all<<<dim3(4096, 7), 256, 0, stream>>>(x_q, x_k, x_v, q_w, k_w, v_w, o_w,
                                                   Xq, Xk, Xv, Wq, Wk, Wv, Wo);
        gemm_qkv2<<<gqkv, 256, 0, stream>>>(Xq, Xk, Xv, Wq, Wk, Wv,
                                            q_b, k_b, v_b, Qp, Kp, VpT);
        attn_kernel<<<ga, 256, 0, stream>>>(Qp, Kp, VpT, msk, Cp);
        gemm_o<true><<<go, 256, 0, stream>>>(Cp, Wo, o_b, out);
    } else {
        // tier 0: Qp Kp VpT Cp (32 MB), f32 staging paths
        ushort_t* Qp = wsu;
        ushort_t* Kp = Qp + NEL;
        ushort_t* VpT = Kp + NEL;
        ushort_t* Cp = VpT + NEL;
        gemm_qkv0<<<gqkv, 256, 0, stream>>>(x_q, x_k, x_v, q_w, k_w, v_w,
                                            q_b, k_b, v_b, Qp, Kp, VpT);
        attn_kernel<<<ga, 256, 0, stream>>>(Qp, Kp, VpT, msk, Cp);
        gemm_o<false><<<go, 256, 0, stream>>>(Cp, o_w, o_b, out);
    }
}